// Round 12
// baseline (376.657 us; speedup 1.0000x reference)
//
#include <hip/hip_runtime.h>
#include <cstdint>
#include <cstddef>

#define FDIM 1024   // feature dim F
#define DDIM 128    // fc out dim D
#define NGRAPH 64   // num graphs B
#define FCH 8       // feature chunks (XCD-local gather)
#define QN 4        // node quarters per graph
#define AGGB (FCH * NGRAPH * QN)   // 2048 aggpool blocks per branch

#define AS1 __attribute__((address_space(1)))
#define AS3 __attribute__((address_space(3)))

typedef float f32x4 __attribute__((ext_vector_type(4)));
typedef short s16x8 __attribute__((ext_vector_type(8)));

__device__ __forceinline__ unsigned short f2bf(float f) {
  unsigned int x = __float_as_uint(f);
  unsigned int r = (x + 0x7fffu + ((x >> 16) & 1u)) >> 16;  // RNE
  return (unsigned short)r;
}
__device__ __forceinline__ float bflo(unsigned int v) {
  return __uint_as_float(v << 16);
}
__device__ __forceinline__ float bfhi(unsigned int v) {
  return __uint_as_float(v & 0xffff0000u);
}

// ===========================================================================
// device building blocks (each kernel composes these; stage-level merges let
// latency/HBM-bound work co-schedule with MFMA/LDS-bound GEMM blocks)
// ===========================================================================

// ---- bf16 MFMA GEMM, 128x128 tile, 4 waves 2x2x(64x64), XCD swizzle ----
__device__ __forceinline__ void dev_gemm(const unsigned short* __restrict__ A,
                                         const unsigned short* __restrict__ Bt,
                                         unsigned short* __restrict__ C,
                                         int M, int bx, int gemmBlocks) {
  __shared__ unsigned short sm[8192];  // As [0,4096) 128x32 ; Bs [4096,8192)
  const int K = FDIM;
  int tid = threadIdx.x;
  int w = tid >> 6, lane = tid & 63;
  int wm = w >> 1, wn = w & 1;

  int per_xcd = gemmBlocks >> 3;
  int l = (bx & 7) * per_xcd + (bx >> 3);
  int m0 = (l >> 3) * 128;   // nt == 8
  int n0 = (l & 7) * 128;

  int sub = lane >> 2;
  int kq = lane & 3;

  f32x4 acc[4][4];
  #pragma unroll
  for (int i = 0; i < 4; ++i)
    #pragma unroll
    for (int j = 0; j < 4; ++j)
      acc[i][j] = (f32x4){0.f, 0.f, 0.f, 0.f};

  for (int k0 = 0; k0 < K; k0 += 32) {
    #pragma unroll
    for (int j = 0; j < 2; ++j) {
      int chunk = w * 2 + j;
      int ra = m0 + chunk * 16 + sub;
      if (ra > M - 1) ra = M - 1;
      const unsigned short* ga = A + (size_t)ra * K + k0 + kq * 8;
      __builtin_amdgcn_global_load_lds((const AS1 unsigned int*)ga,
                                       (AS3 unsigned int*)&sm[chunk * 512], 16, 0, 0);
      int rb = n0 + chunk * 16 + sub;
      const unsigned short* gb = Bt + (size_t)rb * K + k0 + kq * 8;
      __builtin_amdgcn_global_load_lds((const AS1 unsigned int*)gb,
                                       (AS3 unsigned int*)&sm[4096 + chunk * 512], 16, 0, 0);
    }
    __syncthreads();
    s16x8 af[4], bfr[4];
    #pragma unroll
    for (int i = 0; i < 4; ++i) {
      int rowa = wm * 64 + i * 16 + (lane & 15);
      af[i] = *(const s16x8*)&sm[rowa * 32 + (lane >> 4) * 8];
      int rowb = wn * 64 + i * 16 + (lane & 15);
      bfr[i] = *(const s16x8*)&sm[4096 + rowb * 32 + (lane >> 4) * 8];
    }
    #pragma unroll
    for (int i = 0; i < 4; ++i)
      #pragma unroll
      for (int j = 0; j < 4; ++j)
        acc[i][j] = __builtin_amdgcn_mfma_f32_16x16x32_bf16(af[i], bfr[j], acc[i][j], 0, 0, 0);
    __syncthreads();
  }

  #pragma unroll
  for (int i = 0; i < 4; ++i) {
    int row_base = m0 + wm * 64 + i * 16 + (lane >> 4) * 4;
    #pragma unroll
    for (int j = 0; j < 4; ++j) {
      int col = n0 + wn * 64 + j * 16 + (lane & 15);
      #pragma unroll
      for (int r = 0; r < 4; ++r) {
        int row = row_base + r;
        if (row < M) C[(size_t)row * FDIM + col] = f2bf(acc[i][j][r]);
      }
    }
  }
}

// ---- CSR fill (one element i) ----
__device__ __forceinline__ void dev_fill(const int* __restrict__ ei, int* cur,
                                         const float* __restrict__ dinv,
                                         int* adjsrc, float* adjw, int E, int N, int i) {
  if (i < E) {
    int s = ei[i];
    int d = ei[E + i];
    int p = atomicAdd(&cur[d], 1);
    adjsrc[p] = s;
    adjw[p] = dinv[s] * dinv[d];
  }
  if (i < N) {
    int p = atomicAdd(&cur[i], 1);
    adjsrc[p] = i;
    adjw[p] = dinv[i] * dinv[i];
  }
}

// ---- x fp32 -> bf16 (one float4 i) ----
__device__ __forceinline__ void dev_cast_x(const float4* __restrict__ x,
                                           ushort4* xb, int i, int n4) {
  if (i < n4) {
    float4 v = x[i];
    ushort4 o;
    o.x = f2bf(v.x); o.y = f2bf(v.y); o.z = f2bf(v.z); o.w = f2bf(v.w);
    xb[i] = o;
  }
}

// ---- W cast + transpose, one 64x64 tile per block (tid16 in [0,256)) ----
__device__ __forceinline__ void dev_cast_w(const float* __restrict__ W,
                                           unsigned short* Wt, int tid16) {
  __shared__ unsigned short tile[64][65];
  int t = threadIdx.x;
  int kb = tid16 >> 4, nb = tid16 & 15;
  int tn = t & 63, tg = t >> 6;
  #pragma unroll
  for (int r = 0; r < 16; ++r) {
    int kk = tg * 16 + r;
    tile[kk][tn] = f2bf(W[(size_t)(kb * 64 + kk) * FDIM + nb * 64 + tn]);
  }
  __syncthreads();
  #pragma unroll
  for (int r = 0; r < 16; ++r) {
    int nn = tg * 16 + r;
    Wt[(size_t)(nb * 64 + nn) * FDIM + kb * 64 + tn] = tile[tn][nn];
  }
}

// ---- aggpool (XCD-local feature chunks, shfl-broadcast edges, MLP=4) ----
// local block id a in [0, AGGB); chunk = a&7 must align with XCD (offset%8==0)
__device__ __forceinline__ void dev_aggpool(const unsigned short* __restrict__ h,
                                            const int* __restrict__ off,
                                            const int* __restrict__ adjsrc,
                                            const float* __restrict__ adjw,
                                            const float* __restrict__ bias,
                                            const int* __restrict__ cnt,
                                            const int* __restrict__ gstart,
                                            float* pool4, int a) {
  int chunk = a & (FCH - 1);
  int r = a >> 3;
  int g = r & (NGRAPH - 1);
  int q = r >> 6;

  int t = threadIdx.x;
  int grp = t >> 6, lane = t & 63;

  int n = cnt[g];
  int start = gstart[g];
  int per = (n + QN - 1) / QN;
  int v0 = start + q * per;
  int v1 = min(start + n, v0 + per);

  int colbase = chunk * 128 + lane * 2;
  const unsigned short* hc = h + colbase;
  float2 b2 = *(const float2*)(bias + colbase);
  float s0 = 0.f, s1 = 0.f;

  for (int v = v0 + grp; v < v1; v += 4) {
    int pb = off[v], pe = off[v + 1];
    float a0 = 0.f, a1 = 0.f;
    for (int pbb = pb; pbb < pe; pbb += 64) {
      int m = min(64, pe - pbb);
      int lp = pbb + ((lane < m) ? lane : (m - 1));
      int vs = adjsrc[lp];
      float vw = adjw[lp];
      int j = 0;
      for (; j + 4 <= m; j += 4) {
        int i0 = __shfl(vs, j),     i1 = __shfl(vs, j + 1);
        int i2 = __shfl(vs, j + 2), i3 = __shfl(vs, j + 3);
        float w0 = __shfl(vw, j),     w1 = __shfl(vw, j + 1);
        float w2 = __shfl(vw, j + 2), w3 = __shfl(vw, j + 3);
        unsigned int h0 = *(const unsigned int*)(hc + ((size_t)i0 << 10));
        unsigned int hv1 = *(const unsigned int*)(hc + ((size_t)i1 << 10));
        unsigned int hv2 = *(const unsigned int*)(hc + ((size_t)i2 << 10));
        unsigned int hv3 = *(const unsigned int*)(hc + ((size_t)i3 << 10));
        a0 += w0 * bflo(h0);  a1 += w0 * bfhi(h0);
        a0 += w1 * bflo(hv1); a1 += w1 * bfhi(hv1);
        a0 += w2 * bflo(hv2); a1 += w2 * bfhi(hv2);
        a0 += w3 * bflo(hv3); a1 += w3 * bfhi(hv3);
      }
      for (; j < m; ++j) {
        int i0 = __shfl(vs, j);
        float w0 = __shfl(vw, j);
        unsigned int h0 = *(const unsigned int*)(hc + ((size_t)i0 << 10));
        a0 += w0 * bflo(h0);
        a1 += w0 * bfhi(h0);
      }
    }
    a0 += b2.x; a1 += b2.y;
    s0 += (a0 >= 0.f) ? a0 : 0.01f * a0;
    s1 += (a1 >= 0.f) ? a1 : 0.01f * a1;
  }

  __shared__ float smr[4][128];
  smr[grp][lane * 2] = s0;
  smr[grp][lane * 2 + 1] = s1;
  __syncthreads();
  if (t < 128) {
    float sum = smr[0][t] + smr[1][t] + smr[2][t] + smr[3][t];
    float ic = 1.0f / fmaxf((float)n, 1.0f);
    pool4[((size_t)(q * NGRAPH + g)) * FDIM + chunk * 128 + t] = sum * ic;
  }
}

// ===========================================================================
// kernels
// ===========================================================================

// ---- L1: deg=1 both branches + cnt/gstart via binary search ----
__device__ __forceinline__ int lower_bound(const int* a, int n, int v) {
  int lo = 0, hi = n;
  while (lo < hi) {
    int mid = (lo + hi) >> 1;
    if (a[mid] < v) lo = mid + 1; else hi = mid;
  }
  return lo;
}
__global__ __launch_bounds__(256) void k_init(int* deg1, int* deg2,
                                              const int* __restrict__ batch1,
                                              const int* __restrict__ batch2,
                                              int* cnt1, int* gstart1,
                                              int* cnt2, int* gstart2, int N) {
  int bid = blockIdx.x, t = threadIdx.x;
  if (bid < 40) {
    int i = bid * 256 + t;
    if (i < N) deg1[i] = 1;
  } else if (bid < 80) {
    int i = (bid - 40) * 256 + t;
    if (i < N) deg2[i] = 1;
  } else {
    if (t < 128) {
      const int* batch = (t < NGRAPH) ? batch1 : batch2;
      int* cnt = (t < NGRAPH) ? cnt1 : cnt2;
      int* gstart = (t < NGRAPH) ? gstart1 : gstart2;
      int g = t & (NGRAPH - 1);
      int lo = lower_bound(batch, N, g);
      int hi = lower_bound(batch, N, g + 1);
      gstart[g] = lo;
      cnt[g] = hi - lo;
    }
  }
}

// ---- L2: deg atomics (both branches, latency) + cast x1/W1 (HBM) ----
__global__ __launch_bounds__(256) void k_prep_cast1(const int* __restrict__ ei1,
                                                    const int* __restrict__ ei2,
                                                    int* deg1, int* deg2,
                                                    const float4* __restrict__ x1,
                                                    const float* __restrict__ W1,
                                                    ushort4* xb1, unsigned short* Wt1,
                                                    int E, int n4, int gE, int nxb) {
  int x = blockIdx.x, t = threadIdx.x;
  if (x < 2 * gE) {
    int br = x >= gE;
    const int* ei = br ? ei2 : ei1;
    int* deg = br ? deg2 : deg1;
    int i = (x - br * gE) * 256 + t;
    if (i < E) atomicAdd(&deg[ei[E + i]], 1);
  } else if (x < 2 * gE + nxb) {
    dev_cast_x(x1, xb1, (x - 2 * gE) * 256 + t, n4);
  } else {
    dev_cast_w(W1, Wt1, x - 2 * gE - nxb);
  }
}

// ---- L3: exclusive prefix scan per branch ----
#define SCAN_T 1024
#define SCAN_PER 16
__global__ __launch_bounds__(SCAN_T) void k_scan(const int* __restrict__ deg1,
                                                 const int* __restrict__ deg2,
                                                 int* off1, int* off2,
                                                 int* cur1, int* cur2,
                                                 float* dinv1, float* dinv2, int n) {
  const int* deg = blockIdx.x ? deg2 : deg1;
  int* off = blockIdx.x ? off2 : off1;
  int* cur = blockIdx.x ? cur2 : cur1;
  float* dinv = blockIdx.x ? dinv2 : dinv1;
  __shared__ int sums[SCAN_T];
  int t = threadIdx.x;
  int base = t * SCAN_PER;
  int local[SCAN_PER];
  int s = 0;
  #pragma unroll
  for (int i = 0; i < SCAN_PER; ++i) {
    int idx = base + i;
    int d = (idx < n) ? deg[idx] : 0;
    local[i] = s;
    s += d;
    if (idx < n) dinv[idx] = rsqrtf((float)d);
  }
  sums[t] = s;
  __syncthreads();
  for (int o = 1; o < SCAN_T; o <<= 1) {
    int v = (t >= o) ? sums[t - o] : 0;
    __syncthreads();
    sums[t] += v;
    __syncthreads();
  }
  int basesum = (t > 0) ? sums[t - 1] : 0;
  #pragma unroll
  for (int i = 0; i < SCAN_PER; ++i) {
    int idx = base + i;
    if (idx < n) { int o = basesum + local[i]; off[idx] = o; cur[idx] = o; }
  }
  if (t == SCAN_T - 1) off[n] = sums[SCAN_T - 1];
}

// ---- L4: gemm1 (MFMA) + fill both (latency) + cast x2/W2 (HBM) ----
__global__ __launch_bounds__(256) void k_gemm1_fill_cast2(
    const unsigned short* __restrict__ A1, const unsigned short* __restrict__ B1,
    unsigned short* __restrict__ C1,
    const int* __restrict__ ei1, const int* __restrict__ ei2,
    int* cur1, int* cur2,
    const float* __restrict__ dinv1, const float* __restrict__ dinv2,
    int* adjsrc1, int* adjsrc2, float* adjw1, float* adjw2,
    const float4* __restrict__ x2, const float* __restrict__ W2,
    ushort4* xb2, unsigned short* Wt2,
    int E, int N, int n4, int gE, int nxb, int GB) {
  int x = blockIdx.x, t = threadIdx.x;
  if (x < GB) {
    dev_gemm(A1, B1, C1, N, x, GB);
    return;
  }
  int y = x - GB;
  if (y < 2 * gE) {
    int br = y >= gE;
    dev_fill(br ? ei2 : ei1, br ? cur2 : cur1, br ? dinv2 : dinv1,
             br ? adjsrc2 : adjsrc1, br ? adjw2 : adjw1, E, N,
             (y - br * gE) * 256 + t);
    return;
  }
  int z = y - 2 * gE;
  if (z < nxb) {
    dev_cast_x(x2, xb2, z * 256 + t, n4);
  } else {
    dev_cast_w(W2, Wt2, z - nxb);
  }
}

// ---- L5: gemm2 (MFMA) + aggpool branch1 (L2 gather) ----
__global__ __launch_bounds__(256) void k_gemm2_agg1(
    const unsigned short* __restrict__ A2, const unsigned short* __restrict__ B2,
    unsigned short* __restrict__ C2,
    const unsigned short* __restrict__ h1,
    const int* __restrict__ off1, const int* __restrict__ adjsrc1,
    const float* __restrict__ adjw1, const float* __restrict__ bias1,
    const int* __restrict__ cnt1, const int* __restrict__ gstart1,
    float* pool4_1, int N, int GB) {
  int x = blockIdx.x;
  if (x < GB) {
    dev_gemm(A2, B2, C2, N, x, GB);
  } else {
    dev_aggpool(h1, off1, adjsrc1, adjw1, bias1, cnt1, gstart1, pool4_1, x - GB);
  }
}

// ---- L6: aggpool branch2 ----
__global__ __launch_bounds__(256) void k_agg2(const unsigned short* __restrict__ h2,
                                              const int* __restrict__ off2,
                                              const int* __restrict__ adjsrc2,
                                              const float* __restrict__ adjw2,
                                              const float* __restrict__ bias2,
                                              const int* __restrict__ cnt2,
                                              const int* __restrict__ gstart2,
                                              float* pool4_2) {
  dev_aggpool(h2, off2, adjsrc2, adjw2, bias2, cnt2, gstart2, pool4_2, blockIdx.x);
}

// ---- L7: fused heads: fc1 + fc2 + final, one block per graph ----
__global__ __launch_bounds__(DDIM) void k_heads(const float* __restrict__ pool4_1,
                                                const float* __restrict__ pool4_2,
                                                const float* __restrict__ W1,
                                                const float* __restrict__ W2,
                                                const float* __restrict__ b1,
                                                const float* __restrict__ b2,
                                                const float* __restrict__ fW,
                                                const float* __restrict__ fb,
                                                float* __restrict__ out) {
  int g = blockIdx.x;
  int j = threadIdx.x;  // 0..127
  __shared__ float xs[FDIM];
  // branch 1 fc
  for (int k = j; k < FDIM; k += DDIM) {
    float v = 0.f;
    #pragma unroll
    for (int q = 0; q < QN; ++q)
      v += pool4_1[((size_t)(q * NGRAPH + g)) * FDIM + k];
    xs[k] = v;
  }
  __syncthreads();
  float acc1 = b1[j];
  for (int k = 0; k < FDIM; ++k) acc1 += xs[k] * W1[(size_t)k * DDIM + j];
  acc1 = (acc1 >= 0.f) ? acc1 : 0.01f * acc1;
  __syncthreads();
  // branch 2 fc
  for (int k = j; k < FDIM; k += DDIM) {
    float v = 0.f;
    #pragma unroll
    for (int q = 0; q < QN; ++q)
      v += pool4_2[((size_t)(q * NGRAPH + g)) * FDIM + k];
    xs[k] = v;
  }
  __syncthreads();
  float acc2 = b2[j];
  for (int k = 0; k < FDIM; ++k) acc2 += xs[k] * W2[(size_t)k * DDIM + j];
  acc2 = (acc2 >= 0.f) ? acc2 : 0.01f * acc2;
  // final dot over concat dims
  float part = acc1 * fW[j] + acc2 * fW[DDIM + j];
  #pragma unroll
  for (int o = 32; o > 0; o >>= 1) part += __shfl_down(part, o);
  __shared__ float ws2[2];
  if ((j & 63) == 0) ws2[j >> 6] = part;
  __syncthreads();
  if (j == 0) out[g] = ws2[0] + ws2[1] + fb[0];
}

// ---------------------------------------------------------------------------
extern "C" void kernel_launch(void* const* d_in, const int* in_sizes, int n_in,
                              void* d_out, int out_size, void* d_ws, size_t ws_size,
                              hipStream_t stream) {
  const float* x1 = (const float*)d_in[0];
  const int* ei1 = (const int*)d_in[1];
  const int* batch1 = (const int*)d_in[2];
  const float* x2 = (const float*)d_in[3];
  const int* ei2 = (const int*)d_in[4];
  const int* batch2 = (const int*)d_in[5];
  const float* conv1_W = (const float*)d_in[10];
  const float* conv1_b = (const float*)d_in[11];
  const float* fc1_W = (const float*)d_in[12];
  const float* fc1_b = (const float*)d_in[13];
  const float* conv2_W = (const float*)d_in[14];
  const float* conv2_b = (const float*)d_in[15];
  const float* fc2_W = (const float*)d_in[16];
  const float* fc2_b = (const float*)d_in[17];
  const float* final_W = (const float*)d_in[18];
  const float* final_b = (const float*)d_in[19];
  float* out = (float*)d_out;

  const int N = in_sizes[2];      // 10000
  const int E = in_sizes[1] / 2;  // 80000
  const int A = E + N;

  size_t off_b = 0;
  auto alloc = [&](size_t bytes) -> void* {
    void* p = (char*)d_ws + off_b;
    off_b += (bytes + 255) & ~(size_t)255;
    return p;
  };
  unsigned short* xbf1 = (unsigned short*)alloc((size_t)N * FDIM * 2);
  unsigned short* xbf2 = (unsigned short*)alloc((size_t)N * FDIM * 2);
  unsigned short* hbf1 = (unsigned short*)alloc((size_t)N * FDIM * 2);
  unsigned short* hbf2 = (unsigned short*)alloc((size_t)N * FDIM * 2);
  unsigned short* Wt1 = (unsigned short*)alloc((size_t)FDIM * FDIM * 2);
  unsigned short* Wt2 = (unsigned short*)alloc((size_t)FDIM * FDIM * 2);
  int* deg1 = (int*)alloc(N * 4);
  int* deg2 = (int*)alloc(N * 4);
  int* cnt1 = (int*)alloc(NGRAPH * 4);
  int* cnt2 = (int*)alloc(NGRAPH * 4);
  int* gstart1 = (int*)alloc(NGRAPH * 4);
  int* gstart2 = (int*)alloc(NGRAPH * 4);
  int* off1 = (int*)alloc((N + 1) * 4);
  int* off2 = (int*)alloc((N + 1) * 4);
  int* cur1 = (int*)alloc(N * 4);
  int* cur2 = (int*)alloc(N * 4);
  float* dinv1 = (float*)alloc(N * 4);
  float* dinv2 = (float*)alloc(N * 4);
  int* adjsrc1 = (int*)alloc((size_t)A * 4);
  int* adjsrc2 = (int*)alloc((size_t)A * 4);
  float* adjw1 = (float*)alloc((size_t)A * 4);
  float* adjw2 = (float*)alloc((size_t)A * 4);
  float* pool4_1 = (float*)alloc((size_t)QN * NGRAPH * FDIM * 4);
  float* pool4_2 = (float*)alloc((size_t)QN * NGRAPH * FDIM * 4);

  const int T = 256;
  int gE = (E + T - 1) / T;                 // 313
  int n4 = N * FDIM / 4;                    // 2,560,000
  int nxb = (n4 + T - 1) / T;               // 10000
  int mt = (N + 127) / 128;                 // 79
  int GB = mt * 8;                          // 632 gemm blocks (div by 8)

  k_init<<<81, T, 0, stream>>>(deg1, deg2, batch1, batch2,
                               cnt1, gstart1, cnt2, gstart2, N);
  k_prep_cast1<<<2 * gE + nxb + 256, T, 0, stream>>>(ei1, ei2, deg1, deg2,
                                                     (const float4*)x1, conv1_W,
                                                     (ushort4*)xbf1, Wt1,
                                                     E, n4, gE, nxb);
  k_scan<<<2, SCAN_T, 0, stream>>>(deg1, deg2, off1, off2, cur1, cur2, dinv1, dinv2, N);
  k_gemm1_fill_cast2<<<GB + 2 * gE + nxb + 256, T, 0, stream>>>(
      xbf1, Wt1, hbf1,
      ei1, ei2, cur1, cur2, dinv1, dinv2, adjsrc1, adjsrc2, adjw1, adjw2,
      (const float4*)x2, conv2_W, (ushort4*)xbf2, Wt2,
      E, N, n4, gE, nxb, GB);
  k_gemm2_agg1<<<GB + AGGB, T, 0, stream>>>(
      xbf2, Wt2, hbf2,
      hbf1, off1, adjsrc1, adjw1, conv1_b, cnt1, gstart1, pool4_1, N, GB);
  k_agg2<<<AGGB, T, 0, stream>>>(hbf2, off2, adjsrc2, adjw2, conv2_b,
                                 cnt2, gstart2, pool4_2);
  k_heads<<<NGRAPH, DDIM, 0, stream>>>(pool4_1, pool4_2, fc1_W, fc2_W,
                                       fc1_b, fc2_b, final_W, final_b, out);
}